// Round 4
// baseline (598.072 us; speedup 1.0000x reference)
//
#include <hip/hip_runtime.h>
#include <stdint.h>

typedef unsigned short u16;
typedef unsigned int u32;
typedef u16 u16x8 __attribute__((ext_vector_type(8)));
typedef u16 u16x4 __attribute__((ext_vector_type(4)));
typedef u16 u16x2 __attribute__((ext_vector_type(2)));
typedef __bf16 bf16x8 __attribute__((ext_vector_type(8)));
typedef float f32x4 __attribute__((ext_vector_type(4)));

__device__ __forceinline__ float bf2f(u16 u) {
    unsigned int x = ((unsigned int)u) << 16;
    float f; __builtin_memcpy(&f, &x, 4); return f;
}
__device__ __forceinline__ u16 f2bf(float f) {
    unsigned int x; __builtin_memcpy(&x, &f, 4);
    x += 0x7fffu + ((x >> 16) & 1u);   // RNE for finite values
    return (u16)(x >> 16);
}
__device__ __forceinline__ float wsum(float v) {
#pragma unroll
    for (int o = 32; o > 0; o >>= 1) v += __shfl_xor(v, o, 64);
    return v;
}

// async global->LDS, 16B per lane (harness-proven in gemm_bt)
__device__ __forceinline__ void gload16(const void* g, void* l) {
    const __attribute__((address_space(1))) u32* gp =
        reinterpret_cast<const __attribute__((address_space(1))) u32*>(
            reinterpret_cast<uintptr_t>(g));
    __attribute__((address_space(3))) u32* lp =
        reinterpret_cast<__attribute__((address_space(3))) u32*>(
            reinterpret_cast<uintptr_t>(l));
    __builtin_amdgcn_global_load_lds(gp, lp, 16, 0, 0);
}

// ---------------- fast GEMM (m97 structure): C = A @ Bt^T ----------------
// A  [M,K] bf16 row-major, Bt [N,K] bf16 row-major (pre-transposed weights).
// C [M,N]: fp32 (C_F32=1) or bf16 (C_F32=0).
template<int C_F32>
__global__ __launch_bounds__(256) void gemm_bt(
    const u16* __restrict__ A, const u16* __restrict__ Bt,
    void* __restrict__ Cp, int M, int N, int K)
{
    __shared__ __align__(16) u16 sA[128 * 32];   // [m][k], 64B rows
    __shared__ __align__(16) u16 sB[128 * 32];   // [n][k], 64B rows
    const int t = threadIdx.x;
    const int lane = t & 63, wave = t >> 6;
    const int quad = lane >> 4, lr = lane & 15;

    // XCD-aware bijective swizzle (nwg % 8 == 0 for our grids)
    const int nwg = gridDim.x * gridDim.y;
    int id = blockIdx.y * gridDim.x + blockIdx.x;
    int swz = ((nwg & 7) == 0) ? ((id & 7) * (nwg >> 3) + (id >> 3)) : id;
    const int bx = swz % gridDim.x, by = swz / gridDim.x;
    const int m0 = by * 128, n0 = bx * 128;
    const int wm = (wave & 1) * 64, wn = (wave >> 1) * 64;

    const int r0 = t >> 2, kc = (t & 3) * 8;
    const u16* ga = A + (size_t)(m0 + r0) * K + kc;
    const u16* gb = Bt + (size_t)(n0 + r0) * K + kc;
    u16* la = sA + t * 8;
    u16* lb = sB + t * 8;
    const size_t rstride = (size_t)64 * K;

    f32x4 acc[4][4] = {};

    for (int kt = 0; kt < K; kt += 32) {
        __syncthreads();
        gload16(ga + kt, la);
        gload16(ga + kt + rstride, la + 2048);
        gload16(gb + kt, lb);
        gload16(gb + kt + rstride, lb + 2048);
        __syncthreads();

        bf16x8 af[4], bfr[4];
#pragma unroll
        for (int i = 0; i < 4; ++i)
            af[i] = *(const bf16x8*)(sA + (wm + i * 16 + lr) * 32 + quad * 8);
#pragma unroll
        for (int j = 0; j < 4; ++j)
            bfr[j] = *(const bf16x8*)(sB + (wn + j * 16 + lr) * 32 + quad * 8);
#pragma unroll
        for (int i = 0; i < 4; ++i)
#pragma unroll
            for (int j = 0; j < 4; ++j)
                acc[i][j] = __builtin_amdgcn_mfma_f32_16x16x32_bf16(af[i], bfr[j], acc[i][j], 0, 0, 0);
    }
#pragma unroll
    for (int i = 0; i < 4; ++i) {
        int mrow = m0 + wm + i * 16 + quad * 4;
#pragma unroll
        for (int j = 0; j < 4; ++j) {
            int ncol = n0 + wn + j * 16 + lr;
#pragma unroll
            for (int r = 0; r < 4; ++r) {
                if (C_F32) ((float*)Cp)[(size_t)(mrow + r) * N + ncol] = acc[i][j][r];
                else       ((u16*)Cp)[(size_t)(mrow + r) * N + ncol] = f2bf(acc[i][j][r]);
            }
        }
    }
}

// ------- GEMM2 fused with LN2 + residual: out = LN(A@Bt^T + ftb)*g2+b2 + x -------
// A [M,1024] bf16, Bt [1024,1024] bf16. Block = 64 rows x full 1024 cols,
// 512 threads (8 waves as 2m x 4n; wave = 32 rows x 256 cols, acc[2][16]).
// B (2 MB) is L2-resident; y2 never materialized in HBM.
__global__ __launch_bounds__(512) void gemm2_ln2(
    const u16* __restrict__ A, const u16* __restrict__ Bt,
    const float* __restrict__ x, float* __restrict__ out,
    const float* __restrict__ ftb, const float* __restrict__ g2,
    const float* __restrict__ b2, int M, int K)
{
    __shared__ __align__(16) u16 sB[1024 * 32];  // [n][k] 64 KB
    __shared__ __align__(16) u16 sA[64 * 32];    // [m][k] 4 KB
    __shared__ float sStat[64][9];               // per-row partial sums x 4 n-waves
    const int t = threadIdx.x;
    const int lane = t & 63, wave = t >> 6;
    const int quad = lane >> 4, lr = lane & 15;
    const int wm = (wave >> 2) * 32;             // 0 / 32
    const int wn = (wave & 3) * 256;             // 0 / 256 / 512 / 768
    const int m0 = blockIdx.x * 64;

    // staging addresses
    const int brow = t >> 2, kc = (t & 3) * 8;   // B: c = t + r*512 -> row brow+r*128
    const u16* gb = Bt + (size_t)brow * K + kc;
    u16* lb = sB + t * 8;
    const u16* ga = A + (size_t)(m0 + brow) * K + kc;   // A: threads 0..255
    u16* la = sA + t * 8;

    f32x4 acc[2][16] = {};

    for (int kt = 0; kt < K; kt += 32) {
        __syncthreads();
#pragma unroll
        for (int r = 0; r < 8; ++r)
            gload16(gb + (size_t)r * 128 * K + kt, lb + r * 4096);
        if (wave < 4)                             // wave-uniform branch
            gload16(ga + kt, la);
        __syncthreads();

        bf16x8 af0 = *(const bf16x8*)(sA + (wm + 0 * 16 + lr) * 32 + quad * 8);
        bf16x8 af1 = *(const bf16x8*)(sA + (wm + 1 * 16 + lr) * 32 + quad * 8);
#pragma unroll
        for (int j = 0; j < 16; ++j) {
            bf16x8 bf = *(const bf16x8*)(sB + (wn + j * 16 + lr) * 32 + quad * 8);
            acc[0][j] = __builtin_amdgcn_mfma_f32_16x16x32_bf16(af0, bf, acc[0][j], 0, 0, 0);
            acc[1][j] = __builtin_amdgcn_mfma_f32_16x16x32_bf16(af1, bf, acc[1][j], 0, 0, 0);
        }
    }

    // ---- epilogue: per-lane col params ----
    float fv[16], gv[16], bv[16];
#pragma unroll
    for (int j = 0; j < 16; ++j) {
        int col = wn + j * 16 + lr;
        fv[j] = ftb[col]; gv[j] = g2[col]; bv[j] = b2[col];
    }

    // per-lane partial sums over its 16 cols, per (i,r) row
    float ps[2][4], pq[2][4];
#pragma unroll
    for (int i = 0; i < 2; ++i)
#pragma unroll
        for (int r = 0; r < 4; ++r) {
            float s = 0.f, q = 0.f;
#pragma unroll
            for (int j = 0; j < 16; ++j) {
                float y = acc[i][j][r] + fv[j];
                s += y; q += y * y;
            }
            // reduce across lr (16 lanes of the quad) -> wave's 256-col partial
#pragma unroll
            for (int o = 8; o > 0; o >>= 1) {
                s += __shfl_xor(s, o, 64);
                q += __shfl_xor(q, o, 64);
            }
            ps[i][r] = s; pq[i][r] = q;
        }

    __syncthreads();   // sB/sA reads done; also orders sStat use
    if (lr == 0) {
#pragma unroll
        for (int i = 0; i < 2; ++i)
#pragma unroll
            for (int r = 0; r < 4; ++r) {
                int row = wm + i * 16 + quad * 4 + r;
                sStat[row][(wave & 3) * 2 + 0] = ps[i][r];
                sStat[row][(wave & 3) * 2 + 1] = pq[i][r];
            }
    }
    __syncthreads();

#pragma unroll
    for (int i = 0; i < 2; ++i)
#pragma unroll
        for (int r = 0; r < 4; ++r) {
            int row = wm + i * 16 + quad * 4 + r;
            float S  = sStat[row][0] + sStat[row][2] + sStat[row][4] + sStat[row][6];
            float SQ = sStat[row][1] + sStat[row][3] + sStat[row][5] + sStat[row][7];
            float mu = S * (1.f / 1024.f);
            float var = fmaxf(SQ * (1.f / 1024.f) - mu * mu, 0.f);
            float rinv = rsqrtf(var + 1e-5f);
            const size_t grow = (size_t)(m0 + row) * 1024;
#pragma unroll
            for (int j = 0; j < 16; ++j) {
                int col = wn + j * 16 + lr;
                float y = acc[i][j][r] + fv[j];
                out[grow + col] = (y - mu) * rinv * gv[j] + bv[j] + x[grow + col];
            }
        }
}

// ---------------- prep: fp32 -> bf16 streaming convert ----------------
__global__ __launch_bounds__(256) void f32_to_bf16(
    const float* __restrict__ in, u16* __restrict__ out, int n8)
{
    int i = blockIdx.x * 256 + threadIdx.x;
    const int stride = gridDim.x * 256;
    for (; i < n8; i += stride) {
        f32x4 a = *(const f32x4*)(in + (size_t)i * 8);
        f32x4 b = *(const f32x4*)(in + (size_t)i * 8 + 4);
        u16x8 o;
#pragma unroll
        for (int p = 0; p < 4; ++p) { o[p] = f2bf(a[p]); o[p + 4] = f2bf(b[p]); }
        *(u16x8*)(out + (size_t)i * 8) = o;
    }
}

// ---------------- prep: W[K][N] fp32 -> Bt[N][K] bf16 ----------------
__global__ __launch_bounds__(256) void w_transpose(
    const float* __restrict__ W, u16* __restrict__ Bt, int K, int N)
{
    __shared__ u16 tile[64][72];
    const int t = threadIdx.x;
    const int c4 = (t & 15) * 4;
    const int r0 = t >> 4;
    const int kb = blockIdx.y * 64, nb = blockIdx.x * 64;
#pragma unroll
    for (int p = 0; p < 4; ++p) {
        int k = p * 16 + r0;
        f32x4 v = *(const f32x4*)(W + (size_t)(kb + k) * N + nb + c4);
        u16x4 o;
#pragma unroll
        for (int j = 0; j < 4; ++j) o[j] = f2bf(v[j]);
        *(u16x4*)&tile[k][c4] = o;
    }
    __syncthreads();
#pragma unroll
    for (int p = 0; p < 4; ++p) {
        int n = p * 16 + r0;
        u16x4 o;
#pragma unroll
        for (int j = 0; j < 4; ++j) o[j] = tile[c4 + j][n];
        *(u16x4*)(Bt + (size_t)(nb + n) * K + kb + c4) = o;
    }
}

// ---------------- LN1 + hierarchical fusion ----------------
__global__ __launch_bounds__(256) void ln1_fusion(
    const u16* Y, const float* __restrict__ ltb,
    const float* __restrict__ g1, const float* __restrict__ b1,
    const float* __restrict__ masks, const float* __restrict__ emb,
    u16* fused, int ROWS)
{
    const int lane = threadIdx.x & 63;
    const int wid = blockIdx.x * (blockDim.x >> 6) + (threadIdx.x >> 6);
    const int nw = gridDim.x * (blockDim.x >> 6);
    const int h0 = lane * 16;

    float ltbv[16], gv[16], bv[16], ev[4][16];
#pragma unroll
    for (int i = 0; i < 16; ++i) {
        ltbv[i] = ltb[h0 + i];
        gv[i] = g1[h0 + i];
        bv[i] = b1[h0 + i];
    }
#pragma unroll
    for (int n = 0; n < 4; ++n)
#pragma unroll
        for (int i = 0; i < 16; ++i) ev[n][i] = emb[n * 1024 + h0 + i];

    for (int r = wid; r < ROWS; r += nw) {
        const u16* yrow = Y + (size_t)r * 1024 + h0;
        u16x8 v0 = *(const u16x8*)(yrow);
        u16x8 v1 = *(const u16x8*)(yrow + 8);
        float y[16], s = 0.f, sq = 0.f;
#pragma unroll
        for (int i = 0; i < 8; ++i) { y[i] = bf2f(v0[i]) + ltbv[i]; y[i + 8] = bf2f(v1[i]) + ltbv[i + 8]; }
#pragma unroll
        for (int i = 0; i < 16; ++i) { s += y[i]; sq += y[i] * y[i]; }
        s = wsum(s); sq = wsum(sq);
        float mu = s * (1.f / 1024.f);
        float var = fmaxf(sq * (1.f / 1024.f) - mu * mu, 0.f);
        float rinv = rsqrtf(var + 1e-5f);
        float tv[16];
#pragma unroll
        for (int i = 0; i < 16; ++i) tv[i] = (y[i] - mu) * rinv * gv[i] + bv[i];

        float p0 = 0.f, p1 = 0.f, p2 = 0.f, p3 = 0.f;
#pragma unroll
        for (int i = 0; i < 16; ++i) {
            p0 += tv[i] * ev[0][i]; p1 += tv[i] * ev[1][i];
            p2 += tv[i] * ev[2][i]; p3 += tv[i] * ev[3][i];
        }
        p0 = wsum(p0); p1 = wsum(p1); p2 = wsum(p2); p3 = wsum(p3);
        p0 = fminf(p0, 30.f); p1 = fminf(p1, 30.f); p2 = fminf(p2, 30.f); p3 = fminf(p3, 30.f);

        f32x4 mk = *(const f32x4*)(masks + (size_t)r * 4);
        float w0 = mk[0] > 0.5f ? expf(p0) : 0.f;
        float w1 = mk[1] > 0.5f ? expf(p1) : 0.f;
        float w2 = mk[2] > 0.5f ? expf(p2) : 0.f;
        float w3 = mk[3] > 0.5f ? expf(p3) : 0.f;
        float tot = w0 + w1 + w2 + w3;
        float inv = tot > 1e-8f ? 1.f / tot : 1.f;

        float fu[16], d = 0.f;
#pragma unroll
        for (int i = 0; i < 16; ++i) {
            fu[i] = (w0 * ev[0][i] + w1 * ev[1][i] + w2 * ev[2][i] + w3 * ev[3][i]) * inv;
            d += fu[i] * tv[i];
        }
        d = wsum(d);
        float gate = 1.f / (1.f + expf(fminf(-d * (1.f / 1024.f), 30.f)));

        u16x8 o0, o1;
#pragma unroll
        for (int i = 0; i < 8; ++i) {
            o0[i] = f2bf(gate * fu[i] + (1.f - gate) * tv[i]);
            o1[i] = f2bf(gate * fu[i + 8] + (1.f - gate) * tv[i + 8]);
        }
        u16* orow = fused + (size_t)r * 1024 + h0;
        *(u16x8*)(orow) = o0;
        *(u16x8*)(orow + 8) = o1;
    }
}

// ---------------- multi-scale: LDS-staged sliding windows ----------------
#define MS_SEG 64
#define MS_HH 512
#define MS_ROWS (MS_SEG + 14)   // 78 rows, 78*512*2 = 79872 B LDS
__global__ __launch_bounds__(256) void multiscale_slide(
    const u16* __restrict__ fused, u16* __restrict__ agg, int L)
{
    __shared__ __align__(16) u16 sT[MS_ROWS * MS_HH];
    const int t = threadIdx.x;
    const int lane = t & 63, wave = t >> 6;
    const int hhalf = blockIdx.x & 1;
    const int bseg = blockIdx.x >> 1;
    const int nseg = L / MS_SEG;
    const int b = bseg / nseg, seg = bseg - b * nseg;
    const int l0 = seg * MS_SEG;
    const size_t base = (size_t)b * L * 1024 + (size_t)hhalf * MS_HH;

    for (int r = wave; r < MS_ROWS; r += 4) {
        int gl = l0 + r - 7;
        u16x8 v = {};
        if ((unsigned)gl < (unsigned)L)
            v = *(const u16x8*)(fused + base + (size_t)gl * 1024 + lane * 8);
        *(u16x8*)(sT + r * MS_HH + lane * 8) = v;
    }
    __syncthreads();

    const int h0 = lane * 8;
    const int lq = wave;
    const u16* rowp = sT + (lq * 16) * MS_HH + h0;

#define LOADR(dst, rr) { u16x8 _v = *(const u16x8*)(rowp + (rr) * MS_HH); \
    _Pragma("unroll") for (int e = 0; e < 8; ++e) dst[e] = bf2f(_v[e]); }

    float fc[8], a3[8], a7[8], a15[8];
    {
        float u[8], v[8];
        LOADR(fc, 7);
        LOADR(u, 6); LOADR(v, 8);
#pragma unroll
        for (int e = 0; e < 8; ++e) a3[e] = fc[e] + u[e] + v[e];
        LOADR(u, 5); LOADR(v, 9);
#pragma unroll
        for (int e = 0; e < 8; ++e) a7[e] = a3[e] + u[e] + v[e];
        LOADR(u, 4); LOADR(v, 10);
#pragma unroll
        for (int e = 0; e < 8; ++e) a7[e] += u[e] + v[e];
        LOADR(u, 3); LOADR(v, 11);
#pragma unroll
        for (int e = 0; e < 8; ++e) a15[e] = a7[e] + u[e] + v[e];
        LOADR(u, 2); LOADR(v, 12);
#pragma unroll
        for (int e = 0; e < 8; ++e) a15[e] += u[e] + v[e];
        LOADR(u, 1); LOADR(v, 13);
#pragma unroll
        for (int e = 0; e < 8; ++e) a15[e] += u[e] + v[e];
        LOADR(u, 0); LOADR(v, 14);
#pragma unroll
        for (int e = 0; e < 8; ++e) a15[e] += u[e] + v[e];
    }

    const float SW1 = 1.f / (1.f + logf(3.f));
    const float SW2 = 1.f / (1.f + logf(7.f));
    const float SW3 = 1.f / (1.f + logf(15.f));
    const float C1 = SW1 / 3.f, C2 = SW2 / 7.f, C3 = SW3 / 15.f;

    u16* outp = agg + base + (size_t)(l0 + lq * 16) * 1024 + h0;
#pragma unroll
    for (int i = 0; i < 16; ++i) {
        const int l = l0 + lq * 16 + i;
        float c1 = C1, c2 = C2, c3 = C3;
        if (l < 7 || l + 7 >= L) {
            int s1 = l - 1 < 0 ? 0 : l - 1, e1 = l + 2 > L ? L : l + 2;
            int s2 = l - 3 < 0 ? 0 : l - 3, e2 = l + 4 > L ? L : l + 4;
            int s3 = l - 7 < 0 ? 0 : l - 7, e3 = l + 8 > L ? L : l + 8;
            c1 = SW1 / (float)(e1 - s1);
            c2 = SW2 / (float)(e2 - s2);
            c3 = SW3 / (float)(e3 - s3);
        }
        u16x8 o;
#pragma unroll
        for (int e = 0; e < 8; ++e)
            o[e] = f2bf(fc[e] + c1 * a3[e] + c2 * a7[e] + c3 * a15[e]);
        *(u16x8*)(outp + (size_t)i * 1024) = o;

        if (i < 15) {
            float p1[8], p2[8], m1[8], p4[8], m3[8], p8[8], m7[8];
            LOADR(p1, 7 + i + 1); LOADR(p2, 7 + i + 2); LOADR(m1, 7 + i - 1);
            LOADR(p4, 7 + i + 4); LOADR(m3, 7 + i - 3);
            LOADR(p8, 7 + i + 8); LOADR(m7, 7 + i - 7);
#pragma unroll
            for (int e = 0; e < 8; ++e) {
                a3[e]  += p2[e] - m1[e];
                a7[e]  += p4[e] - m3[e];
                a15[e] += p8[e] - m7[e];
                fc[e]   = p1[e];
            }
        }
    }
#undef LOADR
}

// ---------------- fallback GEMM (reg-staged fp32-B, tight-ws only) ----------------
#define BM 128
#define BN 128
#define BKK 32
#define SBS (BN + 2)
__global__ __launch_bounds__(256) void gemm_k_bf_f32(
    const u16* __restrict__ Ap, const float* __restrict__ B,
    float* __restrict__ Cp, int M, int N, int K)
{
    __shared__ __align__(16) u16 sA[BM * BKK];
    __shared__ __align__(16) u16 sB[BKK * SBS];
    const int t = threadIdx.x;
    const int lane = t & 63, wave = t >> 6;
    const int m0 = blockIdx.y * BM, n0 = blockIdx.x * BN;
    const int wm = (wave & 1) * 64, wn = (wave >> 1) * 64;
    const int quad = lane >> 4, lr = lane & 15;

    f32x4 acc[4][4] = {};

    for (int kt = 0; kt < K; kt += BKK) {
        u16x8 va[2], vb[2];
#pragma unroll
        for (int r = 0; r < 2; ++r) {
            int c = t + r * 256;
            int arow = c >> 2, aks = (c & 3) * 8;
            va[r] = *(const u16x8*)(Ap + (size_t)(m0 + arow) * K + kt + aks);
            int bk = c >> 4, bn = (c & 15) * 8;
            const float* gb = B + (size_t)(kt + bk) * N + n0 + bn;
            f32x4 g0 = *(const f32x4*)gb;
            f32x4 g1 = *(const f32x4*)(gb + 4);
#pragma unroll
            for (int p = 0; p < 4; ++p) { vb[r][p] = f2bf(g0[p]); vb[r][p + 4] = f2bf(g1[p]); }
        }
        __syncthreads();
#pragma unroll
        for (int r = 0; r < 2; ++r) {
            int c = t + r * 256;
            *(u16x8*)((char*)sA + (size_t)c * 16) = va[r];
            int bk = c >> 4, bn = (c & 15) * 8;
            u16* dst = sB + bk * SBS + bn;
#pragma unroll
            for (int p = 0; p < 4; ++p) {
                u16x2 w; w[0] = vb[r][2 * p]; w[1] = vb[r][2 * p + 1];
                *(u16x2*)(dst + 2 * p) = w;
            }
        }
        __syncthreads();

        bf16x8 af[4], bfr[4];
#pragma unroll
        for (int i = 0; i < 4; ++i)
            af[i] = *(const bf16x8*)((const char*)sA + (wm + i * 16 + lr) * 64 + quad * 16);
#pragma unroll
        for (int i = 0; i < 4; ++i) {
            u16 tmp[8];
#pragma unroll
            for (int j = 0; j < 8; ++j)
                tmp[j] = sB[(quad * 8 + j) * SBS + (wn + i * 16 + lr)];
            __builtin_memcpy(&bfr[i], tmp, 16);
        }
#pragma unroll
        for (int i = 0; i < 4; ++i)
#pragma unroll
            for (int j = 0; j < 4; ++j)
                acc[i][j] = __builtin_amdgcn_mfma_f32_16x16x32_bf16(af[i], bfr[j], acc[i][j], 0, 0, 0);
    }
#pragma unroll
    for (int i = 0; i < 4; ++i) {
        int mrow = m0 + wm + i * 16 + quad * 4;
#pragma unroll
        for (int j = 0; j < 4; ++j) {
            int ncol = n0 + wn + j * 16 + lr;
#pragma unroll
            for (int r = 0; r < 4; ++r)
                Cp[(size_t)(mrow + r) * N + ncol] = acc[i][j][r];
        }
    }
}

// ---------------- LN2 + residual, fp32 in-place (fallback path only) ----------------
__global__ __launch_bounds__(256) void ln2_res(
    float* Y, const float* __restrict__ ftb,
    const float* __restrict__ g2, const float* __restrict__ b2,
    const float* __restrict__ x, int ROWS)
{
    const int lane = threadIdx.x & 63;
    const int wid = blockIdx.x * (blockDim.x >> 6) + (threadIdx.x >> 6);
    const int nw = gridDim.x * (blockDim.x >> 6);
    const int h0 = lane * 16;

    float ftbv[16], gv[16], bv[16];
#pragma unroll
    for (int i = 0; i < 16; ++i) {
        ftbv[i] = ftb[h0 + i];
        gv[i] = g2[h0 + i];
        bv[i] = b2[h0 + i];
    }
    for (int r = wid; r < ROWS; r += nw) {
        float* yrow = Y + (size_t)r * 1024 + h0;
        float y[16], s = 0.f, sq = 0.f;
#pragma unroll
        for (int q = 0; q < 4; ++q) {
            f32x4 v = *(const f32x4*)(yrow + 4 * q);
#pragma unroll
            for (int p = 0; p < 4; ++p) y[4 * q + p] = v[p] + ftbv[4 * q + p];
        }
#pragma unroll
        for (int i = 0; i < 16; ++i) { s += y[i]; sq += y[i] * y[i]; }
        s = wsum(s); sq = wsum(sq);
        float mu = s * (1.f / 1024.f);
        float var = fmaxf(sq * (1.f / 1024.f) - mu * mu, 0.f);
        float rinv = rsqrtf(var + 1e-5f);

        const float* xrow = x + (size_t)r * 1024 + h0;
#pragma unroll
        for (int q = 0; q < 4; ++q) {
            f32x4 xv = *(const f32x4*)(xrow + 4 * q);
            f32x4 o;
#pragma unroll
            for (int p = 0; p < 4; ++p)
                o[p] = (y[4 * q + p] - mu) * rinv * gv[4 * q + p] + bv[4 * q + p] + xv[p];
            *(f32x4*)(yrow + 4 * q) = o;
        }
    }
}

extern "C" void kernel_launch(void* const* d_in, const int* in_sizes, int n_in,
                              void* d_out, int out_size, void* d_ws, size_t ws_size,
                              hipStream_t stream) {
    const float* x     = (const float*)d_in[0];
    const float* masks = (const float*)d_in[1];
    const float* emb   = (const float*)d_in[2];
    const float* ltw   = (const float*)d_in[3];
    const float* ltb   = (const float*)d_in[4];
    const float* g1    = (const float*)d_in[5];
    const float* b1    = (const float*)d_in[6];
    const float* ftw   = (const float*)d_in[7];
    const float* ftb   = (const float*)d_in[8];
    const float* g2    = (const float*)d_in[9];
    const float* b2    = (const float*)d_in[10];
    float* out = (float*)d_out;                   // [B,L,H] fp32 (128 MB)

    const int H = 1024, L = 4096;
    const int M = in_sizes[0] / H;                // B*L = 32768
    const size_t MB = 1024 * 1024;

    // memory plan:
    //  d_out lower 64 MB : plane0 (bf16 y1 / fused) — dead before out-write of gemm2_ln2
    //  d_out upper 64 MB : x_bf16 (A for GEMM1)     — dead before out-write
    //  ws[0:64MB]        : aggP bf16
    //  ws[64:66MB]       : Bt1; ws[66:68MB] : Bt2 (roomy only)
    //  tight-ws          : Bt1 aliases ws[0:2MB] (dead before agg written);
    //                      GEMM2 falls back to reg-staged fp32-B kernel + ln2_res.
    u16* plane0 = (u16*)d_out;
    u16* xbf    = (u16*)((char*)d_out + 64 * MB);
    u16* aggP   = (u16*)d_ws;
    const bool roomy = ws_size >= 68 * MB;
    u16* Bt1 = roomy ? (u16*)((char*)d_ws + 64 * MB) : (u16*)d_ws;
    u16* Bt2 = roomy ? (u16*)((char*)d_ws + 66 * MB) : nullptr;

    f32_to_bf16<<<2048, 256, 0, stream>>>(x, xbf, M * H / 8);
    w_transpose<<<dim3(16, 16), 256, 0, stream>>>(ltw, Bt1, H, H);
    if (roomy) w_transpose<<<dim3(16, 16), 256, 0, stream>>>(ftw, Bt2, H, H);

    gemm_bt<0><<<dim3(H / 128, M / 128), 256, 0, stream>>>(xbf, Bt1, plane0, M, H, H);  // y1 bf16
    ln1_fusion<<<1024, 256, 0, stream>>>(plane0, ltb, g1, b1, masks, emb, plane0, M);   // fused in-place
    multiscale_slide<<<(M / MS_SEG) * 2, 256, 0, stream>>>(plane0, aggP, L);            // agg -> ws
    if (roomy) {
        gemm2_ln2<<<M / 64, 512, 0, stream>>>(aggP, Bt2, x, out, ftb, g2, b2, M, H);    // fused GEMM2+LN2+res
    } else {
        gemm_k_bf_f32<<<dim3(H / BN, M / BM), 256, 0, stream>>>(aggP, ftw, out, M, H, H);
        ln2_res<<<1024, 256, 0, stream>>>(out, ftb, g2, b2, x, M);
    }
}

// Round 5
// 566.447 us; speedup vs baseline: 1.0558x; 1.0558x over previous
//
#include <hip/hip_runtime.h>
#include <stdint.h>

typedef unsigned short u16;
typedef unsigned int u32;
typedef u16 u16x8 __attribute__((ext_vector_type(8)));
typedef u16 u16x4 __attribute__((ext_vector_type(4)));
typedef u16 u16x2 __attribute__((ext_vector_type(2)));
typedef __bf16 bf16x8 __attribute__((ext_vector_type(8)));
typedef float f32x4 __attribute__((ext_vector_type(4)));

__device__ __forceinline__ float bf2f(u16 u) {
    unsigned int x = ((unsigned int)u) << 16;
    float f; __builtin_memcpy(&f, &x, 4); return f;
}
__device__ __forceinline__ u16 f2bf(float f) {
    unsigned int x; __builtin_memcpy(&x, &f, 4);
    x += 0x7fffu + ((x >> 16) & 1u);   // RNE for finite values
    return (u16)(x >> 16);
}
__device__ __forceinline__ float wsum(float v) {
#pragma unroll
    for (int o = 32; o > 0; o >>= 1) v += __shfl_xor(v, o, 64);
    return v;
}

// async global->LDS, 16B per lane (harness-proven)
__device__ __forceinline__ void gload16(const void* g, void* l) {
    const __attribute__((address_space(1))) u32* gp =
        reinterpret_cast<const __attribute__((address_space(1))) u32*>(
            reinterpret_cast<uintptr_t>(g));
    __attribute__((address_space(3))) u32* lp =
        reinterpret_cast<__attribute__((address_space(3))) u32*>(
            reinterpret_cast<uintptr_t>(l));
    __builtin_amdgcn_global_load_lds(gp, lp, 16, 0, 0);
}

// ---------------- fast GEMM: C = A @ Bt^T, BK=64, XOR-swizzled LDS ----------------
// A  [M,K] bf16 row-major, Bt [N,K] bf16 row-major (pre-transposed weights).
// LDS rows are 128 B (64 bf16). Logical 16B-slot s of row r lives at phys slot
// s ^ (r&7)  (involution). Staging pre-swizzles the GLOBAL source (rule: gload_lds
// dst must stay lane-linear); fragment reads apply the same XOR -> ~conflict-free.
template<int C_F32>
__global__ __launch_bounds__(256) void gemm_bt(
    const u16* __restrict__ A, const u16* __restrict__ Bt,
    void* __restrict__ Cp, int M, int N, int K)
{
    __shared__ __align__(16) u16 sA[128 * 64];   // [m][k], 128B rows, 16 KB
    __shared__ __align__(16) u16 sB[128 * 64];   // [n][k]
    const int t = threadIdx.x;
    const int lane = t & 63, wave = t >> 6;
    const int quad = lane >> 4, lr = lane & 15;

    // XCD-aware bijective swizzle (nwg % 8 == 0 for our grids)
    const int nwg = gridDim.x * gridDim.y;
    int id = blockIdx.y * gridDim.x + blockIdx.x;
    int swz = ((nwg & 7) == 0) ? ((id & 7) * (nwg >> 3) + (id >> 3)) : id;
    const int bx = swz % gridDim.x, by = swz / gridDim.x;
    const int m0 = by * 128, n0 = bx * 128;
    const int wm = (wave & 1) * 64, wn = (wave >> 1) * 64;

    // staging: 4 rounds per matrix; chunk c = t + r*256; row = c>>3 = (t>>3)+r*32,
    // phys slot = t&7; logical k-slot = (t&7) ^ (row&7)  ((r*32)&7 == 0).
    const int rowt = t >> 3;
    const int kcl = (((t & 7) ^ (rowt & 7))) * 8;          // u16 units
    const u16* ga = A + (size_t)(m0 + rowt) * K + kcl;
    const u16* gb = Bt + (size_t)(n0 + rowt) * K + kcl;
    u16* la = sA + t * 8;                                   // + r*2048 per round
    u16* lb = sB + t * 8;
    const size_t rstride = (size_t)32 * K;

    f32x4 acc[4][4] = {};

    for (int kt = 0; kt < K; kt += 64) {
        __syncthreads();                         // prev iter's LDS reads done
#pragma unroll
        for (int r = 0; r < 4; ++r) {
            gload16(ga + kt + r * rstride, la + r * 2048);
            gload16(gb + kt + r * rstride, lb + r * 2048);
        }
        __syncthreads();                         // compiler drains vmcnt before barrier

#pragma unroll
        for (int q = 0; q < 2; ++q) {            // two 32-K subtiles
            const int psl = ((q * 4 + quad) ^ (lr & 7)) * 8;   // phys slot offset (u16)
            bf16x8 af[4], bfr[4];
#pragma unroll
            for (int i = 0; i < 4; ++i)
                af[i] = *(const bf16x8*)(sA + (wm + i * 16 + lr) * 64 + psl);
#pragma unroll
            for (int j = 0; j < 4; ++j)
                bfr[j] = *(const bf16x8*)(sB + (wn + j * 16 + lr) * 64 + psl);
#pragma unroll
            for (int i = 0; i < 4; ++i)
#pragma unroll
                for (int j = 0; j < 4; ++j)
                    acc[i][j] = __builtin_amdgcn_mfma_f32_16x16x32_bf16(af[i], bfr[j], acc[i][j], 0, 0, 0);
        }
    }
    // epilogue: C/D layout col=lane&15, row=quad*4+r
#pragma unroll
    for (int i = 0; i < 4; ++i) {
        int mrow = m0 + wm + i * 16 + quad * 4;
#pragma unroll
        for (int j = 0; j < 4; ++j) {
            int ncol = n0 + wn + j * 16 + lr;
#pragma unroll
            for (int r = 0; r < 4; ++r) {
                if (C_F32) ((float*)Cp)[(size_t)(mrow + r) * N + ncol] = acc[i][j][r];
                else       ((u16*)Cp)[(size_t)(mrow + r) * N + ncol] = f2bf(acc[i][j][r]);
            }
        }
    }
}

// ---------------- prep (single launch): x->bf16 + both weight transposes ----------------
// blocks [0,2048): convert x (M*H fp32 -> bf16)
// blocks [2048,2304): transpose ltw -> Bt1 ; [2304,2560): ftw -> Bt2 (if doFtw)
__global__ __launch_bounds__(256) void prep_all(
    const float* __restrict__ x, u16* __restrict__ xbf,
    const float* __restrict__ ltw, u16* __restrict__ Bt1,
    const float* __restrict__ ftw, u16* __restrict__ Bt2,
    int n8, int doFtw)
{
    __shared__ u16 tile[64][72];
    const int t = threadIdx.x;
    if (blockIdx.x < 2048) {
        int i = blockIdx.x * 256 + t;
        const int stride = 2048 * 256;
        for (; i < n8; i += stride) {
            f32x4 a = *(const f32x4*)(x + (size_t)i * 8);
            f32x4 b = *(const f32x4*)(x + (size_t)i * 8 + 4);
            u16x8 o;
#pragma unroll
            for (int p = 0; p < 4; ++p) { o[p] = f2bf(a[p]); o[p + 4] = f2bf(b[p]); }
            *(u16x8*)(xbf + (size_t)i * 8) = o;
        }
        return;
    }
    int b = blockIdx.x - 2048;
    const int which = b >> 8;                 // 0: ltw, 1: ftw
    if (which == 1 && !doFtw) return;
    const float* W = which ? ftw : ltw;
    u16* Bt = which ? Bt2 : Bt1;
    const int bb = b & 255;
    const int K = 1024, N = 1024;
    const int kb = (bb >> 4) * 64, nb = (bb & 15) * 64;
    const int c4 = (t & 15) * 4;
    const int r0 = t >> 4;
#pragma unroll
    for (int p = 0; p < 4; ++p) {
        int k = p * 16 + r0;
        f32x4 v = *(const f32x4*)(W + (size_t)(kb + k) * N + nb + c4);
        u16x4 o;
#pragma unroll
        for (int j = 0; j < 4; ++j) o[j] = f2bf(v[j]);
        *(u16x4*)&tile[k][c4] = o;
    }
    __syncthreads();
#pragma unroll
    for (int p = 0; p < 4; ++p) {
        int n = p * 16 + r0;
        u16x4 o;
#pragma unroll
        for (int j = 0; j < 4; ++j) o[j] = tile[c4 + j][n];
        *(u16x4*)(Bt + (size_t)(nb + n) * K + kb + c4) = o;
    }
}

// ---------------- LN1 + hierarchical fusion ----------------
__global__ __launch_bounds__(256) void ln1_fusion(
    const u16* Y, const float* __restrict__ ltb,
    const float* __restrict__ g1, const float* __restrict__ b1,
    const float* __restrict__ masks, const float* __restrict__ emb,
    u16* fused, int ROWS)
{
    const int lane = threadIdx.x & 63;
    const int wid = blockIdx.x * (blockDim.x >> 6) + (threadIdx.x >> 6);
    const int nw = gridDim.x * (blockDim.x >> 6);
    const int h0 = lane * 16;

    float ltbv[16], gv[16], bv[16], ev[4][16];
#pragma unroll
    for (int i = 0; i < 16; ++i) {
        ltbv[i] = ltb[h0 + i];
        gv[i] = g1[h0 + i];
        bv[i] = b1[h0 + i];
    }
#pragma unroll
    for (int n = 0; n < 4; ++n)
#pragma unroll
        for (int i = 0; i < 16; ++i) ev[n][i] = emb[n * 1024 + h0 + i];

    for (int r = wid; r < ROWS; r += nw) {
        const u16* yrow = Y + (size_t)r * 1024 + h0;
        u16x8 v0 = *(const u16x8*)(yrow);
        u16x8 v1 = *(const u16x8*)(yrow + 8);
        float y[16], s = 0.f, sq = 0.f;
#pragma unroll
        for (int i = 0; i < 8; ++i) { y[i] = bf2f(v0[i]) + ltbv[i]; y[i + 8] = bf2f(v1[i]) + ltbv[i + 8]; }
#pragma unroll
        for (int i = 0; i < 16; ++i) { s += y[i]; sq += y[i] * y[i]; }
        s = wsum(s); sq = wsum(sq);
        float mu = s * (1.f / 1024.f);
        float var = fmaxf(sq * (1.f / 1024.f) - mu * mu, 0.f);
        float rinv = rsqrtf(var + 1e-5f);
        float tv[16];
#pragma unroll
        for (int i = 0; i < 16; ++i) tv[i] = (y[i] - mu) * rinv * gv[i] + bv[i];

        float p0 = 0.f, p1 = 0.f, p2 = 0.f, p3 = 0.f;
#pragma unroll
        for (int i = 0; i < 16; ++i) {
            p0 += tv[i] * ev[0][i]; p1 += tv[i] * ev[1][i];
            p2 += tv[i] * ev[2][i]; p3 += tv[i] * ev[3][i];
        }
        p0 = wsum(p0); p1 = wsum(p1); p2 = wsum(p2); p3 = wsum(p3);

        f32x4 mk = *(const f32x4*)(masks + (size_t)r * 4);
        float w0 = mk[0] > 0.5f ? expf(fminf(p0, 30.f)) : 0.f;
        float w1 = mk[1] > 0.5f ? expf(fminf(p1, 30.f)) : 0.f;
        float w2 = mk[2] > 0.5f ? expf(fminf(p2, 30.f)) : 0.f;
        float w3 = mk[3] > 0.5f ? expf(fminf(p3, 30.f)) : 0.f;
        float tot = w0 + w1 + w2 + w3;
        float inv = tot > 1e-8f ? 1.f / tot : 1.f;

        // d = sum_h fu_h * tv_h  ==  inv * sum_n w_n * P_n  (P_n = full-row dots,
        // already wave-reduced above) -> no extra wsum / dot pass needed.
        float d = (w0 * p0 + w1 * p1 + w2 * p2 + w3 * p3) * inv;
        float gate = 1.f / (1.f + expf(fminf(-d * (1.f / 1024.f), 30.f)));

        float fu[16];
#pragma unroll
        for (int i = 0; i < 16; ++i)
            fu[i] = (w0 * ev[0][i] + w1 * ev[1][i] + w2 * ev[2][i] + w3 * ev[3][i]) * inv;

        u16x8 o0, o1;
#pragma unroll
        for (int i = 0; i < 8; ++i) {
            o0[i] = f2bf(gate * fu[i] + (1.f - gate) * tv[i]);
            o1[i] = f2bf(gate * fu[i + 8] + (1.f - gate) * tv[i + 8]);
        }
        u16* orow = fused + (size_t)r * 1024 + h0;
        *(u16x8*)(orow) = o0;
        *(u16x8*)(orow + 8) = o1;
    }
}

// ---------------- multi-scale: LDS-staged sliding windows ----------------
#define MS_SEG 64
#define MS_HH 512
#define MS_ROWS (MS_SEG + 14)   // 78 rows, 78*512*2 = 79872 B LDS
__global__ __launch_bounds__(256) void multiscale_slide(
    const u16* __restrict__ fused, u16* __restrict__ agg, int L)
{
    __shared__ __align__(16) u16 sT[MS_ROWS * MS_HH];
    const int t = threadIdx.x;
    const int lane = t & 63, wave = t >> 6;
    const int hhalf = blockIdx.x & 1;
    const int bseg = blockIdx.x >> 1;
    const int nseg = L / MS_SEG;
    const int b = bseg / nseg, seg = bseg - b * nseg;
    const int l0 = seg * MS_SEG;
    const size_t base = (size_t)b * L * 1024 + (size_t)hhalf * MS_HH;

    for (int r = wave; r < MS_ROWS; r += 4) {
        int gl = l0 + r - 7;
        u16x8 v = {};
        if ((unsigned)gl < (unsigned)L)
            v = *(const u16x8*)(fused + base + (size_t)gl * 1024 + lane * 8);
        *(u16x8*)(sT + r * MS_HH + lane * 8) = v;
    }
    __syncthreads();

    const int h0 = lane * 8;
    const int lq = wave;
    const u16* rowp = sT + (lq * 16) * MS_HH + h0;

#define LOADR(dst, rr) { u16x8 _v = *(const u16x8*)(rowp + (rr) * MS_HH); \
    _Pragma("unroll") for (int e = 0; e < 8; ++e) dst[e] = bf2f(_v[e]); }

    float fc[8], a3[8], a7[8], a15[8];
    {
        float u[8], v[8];
        LOADR(fc, 7);
        LOADR(u, 6); LOADR(v, 8);
#pragma unroll
        for (int e = 0; e < 8; ++e) a3[e] = fc[e] + u[e] + v[e];
        LOADR(u, 5); LOADR(v, 9);
#pragma unroll
        for (int e = 0; e < 8; ++e) a7[e] = a3[e] + u[e] + v[e];
        LOADR(u, 4); LOADR(v, 10);
#pragma unroll
        for (int e = 0; e < 8; ++e) a7[e] += u[e] + v[e];
        LOADR(u, 3); LOADR(v, 11);
#pragma unroll
        for (int e = 0; e < 8; ++e) a15[e] = a7[e] + u[e] + v[e];
        LOADR(u, 2); LOADR(v, 12);
#pragma unroll
        for (int e = 0; e < 8; ++e) a15[e] += u[e] + v[e];
        LOADR(u, 1); LOADR(v, 13);
#pragma unroll
        for (int e = 0; e < 8; ++e) a15[e] += u[e] + v[e];
        LOADR(u, 0); LOADR(v, 14);
#pragma unroll
        for (int e = 0; e < 8; ++e) a15[e] += u[e] + v[e];
    }

    const float SW1 = 1.f / (1.f + logf(3.f));
    const float SW2 = 1.f / (1.f + logf(7.f));
    const float SW3 = 1.f / (1.f + logf(15.f));
    const float C1 = SW1 / 3.f, C2 = SW2 / 7.f, C3 = SW3 / 15.f;

    u16* outp = agg + base + (size_t)(l0 + lq * 16) * 1024 + h0;
#pragma unroll
    for (int i = 0; i < 16; ++i) {
        const int l = l0 + lq * 16 + i;
        float c1 = C1, c2 = C2, c3 = C3;
        if (l < 7 || l + 7 >= L) {
            int s1 = l - 1 < 0 ? 0 : l - 1, e1 = l + 2 > L ? L : l + 2;
            int s2 = l - 3 < 0 ? 0 : l - 3, e2 = l + 4 > L ? L : l + 4;
            int s3 = l - 7 < 0 ? 0 : l - 7, e3 = l + 8 > L ? L : l + 8;
            c1 = SW1 / (float)(e1 - s1);
            c2 = SW2 / (float)(e2 - s2);
            c3 = SW3 / (float)(e3 - s3);
        }
        u16x8 o;
#pragma unroll
        for (int e = 0; e < 8; ++e)
            o[e] = f2bf(fc[e] + c1 * a3[e] + c2 * a7[e] + c3 * a15[e]);
        *(u16x8*)(outp + (size_t)i * 1024) = o;

        if (i < 15) {
            float p1[8], p2[8], m1[8], p4[8], m3[8], p8[8], m7[8];
            LOADR(p1, 7 + i + 1); LOADR(p2, 7 + i + 2); LOADR(m1, 7 + i - 1);
            LOADR(p4, 7 + i + 4); LOADR(m3, 7 + i - 3);
            LOADR(p8, 7 + i + 8); LOADR(m7, 7 + i - 7);
#pragma unroll
            for (int e = 0; e < 8; ++e) {
                a3[e]  += p2[e] - m1[e];
                a7[e]  += p4[e] - m3[e];
                a15[e] += p8[e] - m7[e];
                fc[e]   = p1[e];
            }
        }
    }
#undef LOADR
}

// ---------------- fallback GEMM (reg-staged fp32-B, tight-ws only) ----------------
#define BM 128
#define BN 128
#define BKK 32
#define SBS (BN + 2)
__global__ __launch_bounds__(256) void gemm_k_bf_f32(
    const u16* __restrict__ Ap, const float* __restrict__ B,
    float* __restrict__ Cp, int M, int N, int K)
{
    __shared__ __align__(16) u16 sA[BM * BKK];
    __shared__ __align__(16) u16 sB[BKK * SBS];
    const int t = threadIdx.x;
    const int lane = t & 63, wave = t >> 6;
    const int m0 = blockIdx.y * BM, n0 = blockIdx.x * BN;
    const int wm = (wave & 1) * 64, wn = (wave >> 1) * 64;
    const int quad = lane >> 4, lr = lane & 15;

    f32x4 acc[4][4] = {};

    for (int kt = 0; kt < K; kt += BKK) {
        u16x8 va[2], vb[2];
#pragma unroll
        for (int r = 0; r < 2; ++r) {
            int c = t + r * 256;
            int arow = c >> 2, aks = (c & 3) * 8;
            va[r] = *(const u16x8*)(Ap + (size_t)(m0 + arow) * K + kt + aks);
            int bk = c >> 4, bn = (c & 15) * 8;
            const float* gb = B + (size_t)(kt + bk) * N + n0 + bn;
            f32x4 g0 = *(const f32x4*)gb;
            f32x4 g1 = *(const f32x4*)(gb + 4);
#pragma unroll
            for (int p = 0; p < 4; ++p) { vb[r][p] = f2bf(g0[p]); vb[r][p + 4] = f2bf(g1[p]); }
        }
        __syncthreads();
#pragma unroll
        for (int r = 0; r < 2; ++r) {
            int c = t + r * 256;
            *(u16x8*)((char*)sA + (size_t)c * 16) = va[r];
            int bk = c >> 4, bn = (c & 15) * 8;
            u16* dst = sB + bk * SBS + bn;
#pragma unroll
            for (int p = 0; p < 4; ++p) {
                u16x2 w; w[0] = vb[r][2 * p]; w[1] = vb[r][2 * p + 1];
                *(u16x2*)(dst + 2 * p) = w;
            }
        }
        __syncthreads();

        bf16x8 af[4], bfr[4];
#pragma unroll
        for (int i = 0; i < 4; ++i)
            af[i] = *(const bf16x8*)((const char*)sA + (wm + i * 16 + lr) * 64 + quad * 16);
#pragma unroll
        for (int i = 0; i < 4; ++i) {
            u16 tmp[8];
#pragma unroll
            for (int j = 0; j < 8; ++j)
                tmp[j] = sB[(quad * 8 + j) * SBS + (wn + i * 16 + lr)];
            __builtin_memcpy(&bfr[i], tmp, 16);
        }
#pragma unroll
        for (int i = 0; i < 4; ++i)
#pragma unroll
            for (int j = 0; j < 4; ++j)
                acc[i][j] = __builtin_amdgcn_mfma_f32_16x16x32_bf16(af[i], bfr[j], acc[i][j], 0, 0, 0);
    }
#pragma unroll
    for (int i = 0; i < 4; ++i) {
        int mrow = m0 + wm + i * 16 + quad * 4;
#pragma unroll
        for (int j = 0; j < 4; ++j) {
            int ncol = n0 + wn + j * 16 + lr;
#pragma unroll
            for (int r = 0; r < 4; ++r)
                Cp[(size_t)(mrow + r) * N + ncol] = acc[i][j][r];
        }
    }
}

// ---------------- LN2 + residual, fp32 in-place on d_out ----------------
__global__ __launch_bounds__(256) void ln2_res(
    float* Y, const float* __restrict__ ftb,
    const float* __restrict__ g2, const float* __restrict__ b2,
    const float* __restrict__ x, int ROWS)
{
    const int lane = threadIdx.x & 63;
    const int wid = blockIdx.x * (blockDim.x >> 6) + (threadIdx.x >> 6);
    const int nw = gridDim.x * (blockDim.x >> 6);
    const int h0 = lane * 16;

    float ftbv[16], gv[16], bv[16];
#pragma unroll
    for (int i = 0; i < 16; ++i) {
        ftbv[i] = ftb[h0 + i];
        gv[i] = g2[h0 + i];
        bv[i] = b2[h0 + i];
    }
    for (int r = wid; r < ROWS; r += nw) {
        float* yrow = Y + (size_t)r * 1024 + h0;
        float y[16], s = 0.f, sq = 0.f;
#pragma unroll
        for (int q = 0; q < 4; ++q) {
            f32x4 v = *(const f32x4*)(yrow + 4 * q);
#pragma unroll
            for (int p = 0; p < 4; ++p) y[4 * q + p] = v[p] + ftbv[4 * q + p];
        }
#pragma unroll
        for (int i = 0; i < 16; ++i) { s += y[i]; sq += y[i] * y[i]; }
        s = wsum(s); sq = wsum(sq);
        float mu = s * (1.f / 1024.f);
        float var = fmaxf(sq * (1.f / 1024.f) - mu * mu, 0.f);
        float rinv = rsqrtf(var + 1e-5f);

        const float* xrow = x + (size_t)r * 1024 + h0;
#pragma unroll
        for (int q = 0; q < 4; ++q) {
            f32x4 xv = *(const f32x4*)(xrow + 4 * q);
            f32x4 o;
#pragma unroll
            for (int p = 0; p < 4; ++p)
                o[p] = (y[4 * q + p] - mu) * rinv * gv[4 * q + p] + bv[4 * q + p] + xv[p];
            *(f32x4*)(yrow + 4 * q) = o;
        }
    }
}

extern "C" void kernel_launch(void* const* d_in, const int* in_sizes, int n_in,
                              void* d_out, int out_size, void* d_ws, size_t ws_size,
                              hipStream_t stream) {
    const float* x     = (const float*)d_in[0];
    const float* masks = (const float*)d_in[1];
    const float* emb   = (const float*)d_in[2];
    const float* ltw   = (const float*)d_in[3];
    const float* ltb   = (const float*)d_in[4];
    const float* g1    = (const float*)d_in[5];
    const float* b1    = (const float*)d_in[6];
    const float* ftw   = (const float*)d_in[7];
    const float* ftb   = (const float*)d_in[8];
    const float* g2    = (const float*)d_in[9];
    const float* b2    = (const float*)d_in[10];
    float* out = (float*)d_out;                   // [B,L,H] fp32 (128 MB)

    const int H = 1024, L = 4096;
    const int M = in_sizes[0] / H;                // B*L = 32768
    const size_t MB = 1024 * 1024;

    // memory plan:
    //  d_out lower 64 MB : plane0 (bf16 y1 / fused) — dead before fp32 C-write of GEMM2
    //  d_out upper 64 MB : x_bf16 (A for GEMM1)     — dead before GEMM2's C-write
    //  ws[0:64MB]        : aggP bf16
    //  ws[64:66MB]       : Bt1; ws[66:68MB] : Bt2 (roomy only)
    //  tight-ws          : Bt1 aliases ws[0:2MB] (dead before agg written);
    //                      GEMM2 falls back to reg-staged fp32-B kernel + ln2_res.
    u16* plane0 = (u16*)d_out;
    u16* xbf    = (u16*)((char*)d_out + 64 * MB);
    u16* aggP   = (u16*)d_ws;
    const bool roomy = ws_size >= 68 * MB;
    u16* Bt1 = roomy ? (u16*)((char*)d_ws + 64 * MB) : (u16*)d_ws;
    u16* Bt2 = roomy ? (u16*)((char*)d_ws + 66 * MB) : nullptr;

    prep_all<<<2048 + 512, 256, 0, stream>>>(x, xbf, ltw, Bt1, ftw, Bt2, M * H / 8, roomy ? 1 : 0);

    gemm_bt<0><<<dim3(H / 128, M / 128), 256, 0, stream>>>(xbf, Bt1, plane0, M, H, H);  // y1 bf16
    ln1_fusion<<<1024, 256, 0, stream>>>(plane0, ltb, g1, b1, masks, emb, plane0, M);   // fused in-place
    multiscale_slide<<<(M / MS_SEG) * 2, 256, 0, stream>>>(plane0, aggP, L);            // agg -> ws
    if (roomy)
        gemm_bt<1><<<dim3(H / 128, M / 128), 256, 0, stream>>>(aggP, Bt2, out, M, H, H);
    else
        gemm_k_bf_f32<<<dim3(H / BN, M / BM), 256, 0, stream>>>(aggP, ftw, out, M, H, H);
    ln2_res<<<1024, 256, 0, stream>>>(out, ftb, g2, b2, x, M);
}